// Round 5
// baseline (241.106 us; speedup 1.0000x reference)
//
#include <hip/hip_runtime.h>
#include <hip/hip_bf16.h>
#include <hip/hip_fp16.h>

#define NNODES 20000
#define NEDGES 320000
#define DIM    128
#define NH     4
#define ETOT   (NEDGES + NNODES)
#define LN_EPS 1e-5f

typedef unsigned short u16;
typedef unsigned int   u32;

typedef _Float16 f16x2 __attribute__((ext_vector_type(2)));
typedef _Float16 f16x8 __attribute__((ext_vector_type(8)));
typedef float    f32x2 __attribute__((ext_vector_type(2)));
typedef float    f32x4 __attribute__((ext_vector_type(4)));

__device__ inline u16 f2h(float f) {
    _Float16 h = (_Float16)f;
    union { _Float16 h; u16 u; } v; v.h = h; return v.u;
}
__device__ inline f16x2 u2h2(u32 u) { union { u32 u; f16x2 h; } v; v.u = u; return v.h; }
__device__ inline u32 h22u(f16x2 h) { union { f16x2 h; u32 u; } v; v.h = h; return v.u; }
__device__ inline f16x2 habs2(f16x2 h) { return u2h2(h22u(h) & 0x7FFF7FFFu); }

// ---------------- CSR build ----------------

__global__ void k_init_deg(int* __restrict__ deg) {
    int i = blockIdx.x * blockDim.x + threadIdx.x;
    if (i < NNODES) deg[i] = 1;   // self-loop
}

__global__ void k_hist(const int* __restrict__ dst, int* __restrict__ deg) {
    int i = blockIdx.x * blockDim.x + threadIdx.x;
    if (i < NEDGES) atomicAdd(&deg[dst[i]], 1);
}

__global__ __launch_bounds__(1024) void k_scan(const int* __restrict__ deg,
                                               int* __restrict__ row,
                                               int* __restrict__ cur) {
    __shared__ int part[1024];
    const int CH = (NNODES + 1023) / 1024;  // 20
    int t = threadIdx.x;
    int base = t * CH;
    int s = 0;
    for (int i = 0; i < CH; i++) { int idx = base + i; if (idx < NNODES) s += deg[idx]; }
    part[t] = s;
    __syncthreads();
    for (int off = 1; off < 1024; off <<= 1) {
        int v = (t >= off) ? part[t - off] : 0;
        __syncthreads();
        part[t] += v;
        __syncthreads();
    }
    int run = (t == 0) ? 0 : part[t - 1];
    for (int i = 0; i < CH; i++) {
        int idx = base + i;
        if (idx < NNODES) { row[idx] = run; cur[idx] = run; run += deg[idx]; }
    }
    if (t == 1023) row[NNODES] = part[1023];
}

__global__ void k_scatter(const int* __restrict__ src, const int* __restrict__ dst,
                          int* __restrict__ col, int* __restrict__ cur) {
    int i = blockIdx.x * blockDim.x + threadIdx.x;
    if (i < NEDGES) {
        int d = dst[i];
        int pos = atomicAdd(&cur[d], 1);
        col[pos] = src[i];
    } else if (i < ETOT) {
        int n = i - NEDGES;
        int pos = atomicAdd(&cur[n], 1);
        col[pos] = n;
    }
}

// ---------------- conversions (f32 -> fp16) ----------------

__global__ void k_cvt_x(const float* __restrict__ in, u16* __restrict__ out, int n4) {
    int i = blockIdx.x * blockDim.x + threadIdx.x;
    if (i < n4) {
        float4 v = ((const float4*)in)[i];
        ushort4 o;
        o.x = f2h(v.x); o.y = f2h(v.y); o.z = f2h(v.z); o.w = f2h(v.w);
        ((ushort4*)out)[i] = o;
    }
}

// Bt[n][k] = (n<512 ? Wl[k][n] : Wr[k][n-512]),  n in [0,1024), k in [0,128)
__global__ void k_cvt_w(const float* __restrict__ Wl, const float* __restrict__ Wr,
                        u16* __restrict__ Bt) {
    int idx = blockIdx.x * blockDim.x + threadIdx.x;
    if (idx < 1024 * 128) {
        int n = idx >> 7, k = idx & 127;
        float v = (n < 512) ? Wl[k * 512 + n] : Wr[k * 512 + (n - 512)];
        Bt[idx] = f2h(v);
    }
}

// ------------- fp16 MFMA GEMM: C[M,1024] = A[M,128] @ Bt^T, Bt is [1024][128] -------------
// 128x128 tile, K=128 single shot, 4 waves (2x2 of 64x64), operand-swapped MFMA.
// A staged in 32KB swizzled LDS; B fragments read directly from global (L2-resident 256KB);
// C stored directly from acc (no LDS round-trip). launch_bounds(256,4) -> <=128 VGPR.

__global__ __launch_bounds__(256, 4) void k_gemm_f16(const u16* __restrict__ A,
                                                     const u16* __restrict__ Bt,
                                                     u16* __restrict__ C, int M) {
    __shared__ u16 smA[128 * 128];   // 32 KB
    const int t  = threadIdx.x;
    const int bm = blockIdx.y * 128;
    const int bn = blockIdx.x * 128;

    // stage A tile, XOR-swizzled rows (byte ^= (row&7)<<4)
    {
        int r  = t >> 4;           // 0..15
        int cb = (t & 15) * 16;    // byte col 0..240
#pragma unroll
        for (int p = 0; p < 8; ++p) {
            int row  = p * 16 + r;
            int grow = bm + row; if (grow > M - 1) grow = M - 1;  // clamp; guarded at store
            uint4 va = *(const uint4*)(A + (size_t)grow * 128 + (cb >> 1));
            *(uint4*)((char*)smA + ((row * 256 + cb) ^ ((row & 7) << 4))) = va;
        }
    }

    const int w   = t >> 6;             // wave 0..3
    const int l   = t & 63;
    const int wr  = (w >> 1) * 64;      // M offset of wave subtile
    const int wc  = (w & 1) * 64;       // N offset
    const int lr  = l & 15;
    const int lkb = (l >> 4) * 16;      // byte offset of lane's k-chunk
    const int lkh = (l >> 4) * 8;       // same in halves

    __syncthreads();

    f32x4 acc[4][4] = {};               // [mi][ni], holds C^T fragments

#pragma unroll
    for (int ks = 0; ks < 4; ++ks) {
        // B fragments for this k-step straight from global (L2 hit)
        f16x8 bfr[4];
#pragma unroll
        for (int ni = 0; ni < 4; ++ni)
            bfr[ni] = *(const f16x8*)(Bt + (size_t)(bn + wc + ni * 16 + lr) * 128
                                         + ks * 32 + lkh);
        f16x8 af[4];
#pragma unroll
        for (int i = 0; i < 4; ++i) {
            int ra = wr + i * 16 + lr;
            af[i]  = *(const f16x8*)((const char*)smA +
                        ((ra * 256 + ks * 64 + lkb) ^ ((ra & 7) << 4)));
        }
#pragma unroll
        for (int mi = 0; mi < 4; ++mi)
#pragma unroll
            for (int ni = 0; ni < 4; ++ni)
                acc[mi][ni] = __builtin_amdgcn_mfma_f32_16x16x32_f16(
                    bfr[ni], af[mi], acc[mi][ni], 0, 0, 0);
    }

    // epilogue: direct stores (per (mi,ni): 16 rows x 32B contiguous per 4 lanes)
    const int n4 = (l >> 4) * 4;
#pragma unroll
    for (int mi = 0; mi < 4; ++mi) {
        int m = bm + wr + mi * 16 + lr;
        if (m < M) {
#pragma unroll
            for (int ni = 0; ni < 4; ++ni) {
                int n = bn + wc + ni * 16 + n4;
                f32x4 v = acc[mi][ni];
                ushort4 o;
                o.x = f2h(v[0]); o.y = f2h(v[1]); o.z = f2h(v[2]); o.w = f2h(v[3]);
                *(ushort4*)(C + (size_t)m * 1024 + n) = o;
            }
        }
    }
}

// ------------- fused GATv2 attention + head-mean + bias + LN + residual -------------
// one WAVE per node (4 heads x 16 lanes, 8 dims/lane), block = 4 waves = 4 nodes.
// xlr fp16 [N][1024]: cols 0..511 = xl, 512..1023 = xr. No-max softmax.
// 4-edge unroll for memory-level parallelism.

__global__ __launch_bounds__(256) void k_attn(const u16* __restrict__ xlr,
                                              const float* __restrict__ att,
                                              const float* __restrict__ bias,
                                              const float* __restrict__ gamma,
                                              const float* __restrict__ beta,
                                              const int* __restrict__ row,
                                              const int* __restrict__ col,
                                              const float* __restrict__ res,
                                              float* __restrict__ out,
                                              u16* __restrict__ out_h,
                                              int relu_flag) {
    const int wid = __builtin_amdgcn_readfirstlane(threadIdx.x >> 6);
    const int n   = blockIdx.x * 4 + wid;          // grid = NNODES/4 exactly
    const int l   = threadIdx.x & 63;
    const int h   = l >> 4;                         // head 0..3
    const int e   = l & 15;                         // dim group: dims e*8..e*8+7

    const f16x2 C06 = {(_Float16)0.6f, (_Float16)0.6f};
    const f16x2 C04 = {(_Float16)0.4f, (_Float16)0.4f};

    uint4 xru = *(const uint4*)(xlr + (size_t)n * 1024 + 512 + h * 128 + e * 8);
    f16x2 xr0 = u2h2(xru.x), xr1 = u2h2(xru.y), xr2 = u2h2(xru.z), xr3 = u2h2(xru.w);

    const float* ap = att + h * 128 + e * 8;
    float4 af0 = *(const float4*)(ap);
    float4 af1 = *(const float4*)(ap + 4);
    f16x2 at0 = {(_Float16)af0.x, (_Float16)af0.y};
    f16x2 at1 = {(_Float16)af0.z, (_Float16)af0.w};
    f16x2 at2 = {(_Float16)af1.x, (_Float16)af1.y};
    f16x2 at3 = {(_Float16)af1.z, (_Float16)af1.w};

    float acc[8] = {0.f,0.f,0.f,0.f,0.f,0.f,0.f,0.f};
    float ssum = 0.f;

    const int beg = row[n], end = row[n + 1];
    const size_t lane_off = h * 128 + e * 8;

    for (int i = beg; i < end; i += 4) {
        int s0 = col[i];
        int s1 = (i + 1 < end) ? col[i + 1] : s0;
        int s2 = (i + 2 < end) ? col[i + 2] : s0;
        int s3 = (i + 3 < end) ? col[i + 3] : s0;
        uint4 a0 = *(const uint4*)(xlr + (size_t)s0 * 1024 + lane_off);
        uint4 a1 = *(const uint4*)(xlr + (size_t)s1 * 1024 + lane_off);
        uint4 a2 = *(const uint4*)(xlr + (size_t)s2 * 1024 + lane_off);
        uint4 a3 = *(const uint4*)(xlr + (size_t)s3 * 1024 + lane_off);

        float e0, e1, e2, e3;
        {
            f16x2 v0 = u2h2(a0.x) + xr0, v1 = u2h2(a0.y) + xr1;
            f16x2 v2 = u2h2(a0.z) + xr2, v3 = u2h2(a0.w) + xr3;
            f16x2 k0 = v0 * C06 + habs2(v0) * C04;
            f16x2 k1 = v1 * C06 + habs2(v1) * C04;
            f16x2 k2 = v2 * C06 + habs2(v2) * C04;
            f16x2 k3 = v3 * C06 + habs2(v3) * C04;
            e0 = __builtin_amdgcn_fdot2(k0, at0, 0.f, false);
            e0 = __builtin_amdgcn_fdot2(k1, at1, e0, false);
            e0 = __builtin_amdgcn_fdot2(k2, at2, e0, false);
            e0 = __builtin_amdgcn_fdot2(k3, at3, e0, false);
        }
        {
            f16x2 v0 = u2h2(a1.x) + xr0, v1 = u2h2(a1.y) + xr1;
            f16x2 v2 = u2h2(a1.z) + xr2, v3 = u2h2(a1.w) + xr3;
            f16x2 k0 = v0 * C06 + habs2(v0) * C04;
            f16x2 k1 = v1 * C06 + habs2(v1) * C04;
            f16x2 k2 = v2 * C06 + habs2(v2) * C04;
            f16x2 k3 = v3 * C06 + habs2(v3) * C04;
            e1 = __builtin_amdgcn_fdot2(k0, at0, 0.f, false);
            e1 = __builtin_amdgcn_fdot2(k1, at1, e1, false);
            e1 = __builtin_amdgcn_fdot2(k2, at2, e1, false);
            e1 = __builtin_amdgcn_fdot2(k3, at3, e1, false);
        }
        {
            f16x2 v0 = u2h2(a2.x) + xr0, v1 = u2h2(a2.y) + xr1;
            f16x2 v2 = u2h2(a2.z) + xr2, v3 = u2h2(a2.w) + xr3;
            f16x2 k0 = v0 * C06 + habs2(v0) * C04;
            f16x2 k1 = v1 * C06 + habs2(v1) * C04;
            f16x2 k2 = v2 * C06 + habs2(v2) * C04;
            f16x2 k3 = v3 * C06 + habs2(v3) * C04;
            e2 = __builtin_amdgcn_fdot2(k0, at0, 0.f, false);
            e2 = __builtin_amdgcn_fdot2(k1, at1, e2, false);
            e2 = __builtin_amdgcn_fdot2(k2, at2, e2, false);
            e2 = __builtin_amdgcn_fdot2(k3, at3, e2, false);
        }
        {
            f16x2 v0 = u2h2(a3.x) + xr0, v1 = u2h2(a3.y) + xr1;
            f16x2 v2 = u2h2(a3.z) + xr2, v3 = u2h2(a3.w) + xr3;
            f16x2 k0 = v0 * C06 + habs2(v0) * C04;
            f16x2 k1 = v1 * C06 + habs2(v1) * C04;
            f16x2 k2 = v2 * C06 + habs2(v2) * C04;
            f16x2 k3 = v3 * C06 + habs2(v3) * C04;
            e3 = __builtin_amdgcn_fdot2(k0, at0, 0.f, false);
            e3 = __builtin_amdgcn_fdot2(k1, at1, e3, false);
            e3 = __builtin_amdgcn_fdot2(k2, at2, e3, false);
            e3 = __builtin_amdgcn_fdot2(k3, at3, e3, false);
        }

#pragma unroll
        for (int m = 1; m < 16; m <<= 1) {
            e0 += __shfl_xor(e0, m, 64);
            e1 += __shfl_xor(e1, m, 64);
            e2 += __shfl_xor(e2, m, 64);
            e3 += __shfl_xor(e3, m, 64);
        }

        float p0 = __expf(e0);
        float p1 = (i + 1 < end) ? __expf(e1) : 0.f;
        float p2 = (i + 2 < end) ? __expf(e2) : 0.f;
        float p3 = (i + 3 < end) ? __expf(e3) : 0.f;
        ssum += (p0 + p1) + (p2 + p3);

        f32x2 f;
        f = __builtin_convertvector(u2h2(a0.x), f32x2); acc[0] += p0*f[0]; acc[1] += p0*f[1];
        f = __builtin_convertvector(u2h2(a0.y), f32x2); acc[2] += p0*f[0]; acc[3] += p0*f[1];
        f = __builtin_convertvector(u2h2(a0.z), f32x2); acc[4] += p0*f[0]; acc[5] += p0*f[1];
        f = __builtin_convertvector(u2h2(a0.w), f32x2); acc[6] += p0*f[0]; acc[7] += p0*f[1];
        f = __builtin_convertvector(u2h2(a1.x), f32x2); acc[0] += p1*f[0]; acc[1] += p1*f[1];
        f = __builtin_convertvector(u2h2(a1.y), f32x2); acc[2] += p1*f[0]; acc[3] += p1*f[1];
        f = __builtin_convertvector(u2h2(a1.z), f32x2); acc[4] += p1*f[0]; acc[5] += p1*f[1];
        f = __builtin_convertvector(u2h2(a1.w), f32x2); acc[6] += p1*f[0]; acc[7] += p1*f[1];
        f = __builtin_convertvector(u2h2(a2.x), f32x2); acc[0] += p2*f[0]; acc[1] += p2*f[1];
        f = __builtin_convertvector(u2h2(a2.y), f32x2); acc[2] += p2*f[0]; acc[3] += p2*f[1];
        f = __builtin_convertvector(u2h2(a2.z), f32x2); acc[4] += p2*f[0]; acc[5] += p2*f[1];
        f = __builtin_convertvector(u2h2(a2.w), f32x2); acc[6] += p2*f[0]; acc[7] += p2*f[1];
        f = __builtin_convertvector(u2h2(a3.x), f32x2); acc[0] += p3*f[0]; acc[1] += p3*f[1];
        f = __builtin_convertvector(u2h2(a3.y), f32x2); acc[2] += p3*f[0]; acc[3] += p3*f[1];
        f = __builtin_convertvector(u2h2(a3.z), f32x2); acc[4] += p3*f[0]; acc[5] += p3*f[1];
        f = __builtin_convertvector(u2h2(a3.w), f32x2); acc[6] += p3*f[0]; acc[7] += p3*f[1];
    }

    // normalize per head, then mean over heads via butterfly across 16/32
    float inv = 1.f / (ssum + 1e-16f);
#pragma unroll
    for (int j = 0; j < 8; ++j) acc[j] *= inv;
#pragma unroll
    for (int j = 0; j < 8; ++j) acc[j] += __shfl_xor(acc[j], 16, 64);
#pragma unroll
    for (int j = 0; j < 8; ++j) acc[j] += __shfl_xor(acc[j], 32, 64);

    if (h == 0) {
        const int dd = e * 8;
        float4 b40 = *(const float4*)(bias + dd);
        float4 b41 = *(const float4*)(bias + dd + 4);
        float y[8];
        y[0] = acc[0]*0.25f + b40.x; y[1] = acc[1]*0.25f + b40.y;
        y[2] = acc[2]*0.25f + b40.z; y[3] = acc[3]*0.25f + b40.w;
        y[4] = acc[4]*0.25f + b41.x; y[5] = acc[5]*0.25f + b41.y;
        y[6] = acc[6]*0.25f + b41.z; y[7] = acc[7]*0.25f + b41.w;

        float s1 = 0.f, s2 = 0.f;
#pragma unroll
        for (int j = 0; j < 8; ++j) { s1 += y[j]; s2 += y[j]*y[j]; }
#pragma unroll
        for (int m = 1; m < 16; m <<= 1) {
            s1 += __shfl_xor(s1, m, 64);
            s2 += __shfl_xor(s2, m, 64);
        }
        float mu = s1 * (1.f / 128.f);
        float var = s2 * (1.f / 128.f) - mu * mu;
        float rstd = rsqrtf(var + LN_EPS);

        float4 g40 = *(const float4*)(gamma + dd);
        float4 g41 = *(const float4*)(gamma + dd + 4);
        float4 e40 = *(const float4*)(beta + dd);
        float4 e41 = *(const float4*)(beta + dd + 4);
        float4 r40 = *(const float4*)(res + (size_t)n * 128 + dd);
        float4 r41 = *(const float4*)(res + (size_t)n * 128 + dd + 4);
        float g[8] = {g40.x,g40.y,g40.z,g40.w,g41.x,g41.y,g41.z,g41.w};
        float be[8] = {e40.x,e40.y,e40.z,e40.w,e41.x,e41.y,e41.z,e41.w};
        float r[8] = {r40.x,r40.y,r40.z,r40.w,r41.x,r41.y,r41.z,r41.w};
#pragma unroll
        for (int j = 0; j < 8; ++j) {
            y[j] = (y[j] - mu) * rstd * g[j] + be[j] + r[j];
            if (relu_flag) y[j] = fmaxf(y[j], 0.f);
        }
        float4 o0 = {y[0],y[1],y[2],y[3]};
        float4 o1 = {y[4],y[5],y[6],y[7]};
        *(float4*)(out + (size_t)n * 128 + dd)     = o0;
        *(float4*)(out + (size_t)n * 128 + dd + 4) = o1;
        if (out_h) {
            ushort4 oh0, oh1;
            oh0.x = f2h(y[0]); oh0.y = f2h(y[1]); oh0.z = f2h(y[2]); oh0.w = f2h(y[3]);
            oh1.x = f2h(y[4]); oh1.y = f2h(y[5]); oh1.z = f2h(y[6]); oh1.w = f2h(y[7]);
            *(ushort4*)(out_h + (size_t)n * 128 + dd)     = oh0;
            *(ushort4*)(out_h + (size_t)n * 128 + dd + 4) = oh1;
        }
    }
}

// ---------------- launch ----------------

extern "C" void kernel_launch(void* const* d_in, const int* in_sizes, int n_in,
                              void* d_out, int out_size, void* d_ws, size_t ws_size,
                              hipStream_t stream) {
    const float* x    = (const float*)d_in[0];
    const int*   src  = (const int*)d_in[1];
    const int*   dst  = (const int*)d_in[2];
    const float* Wl1  = (const float*)d_in[3];
    const float* Wr1  = (const float*)d_in[4];
    const float* att1 = (const float*)d_in[5];
    const float* b1   = (const float*)d_in[6];
    const float* g1   = (const float*)d_in[7];
    const float* be1  = (const float*)d_in[8];
    const float* Wl2  = (const float*)d_in[9];
    const float* Wr2  = (const float*)d_in[10];
    const float* att2 = (const float*)d_in[11];
    const float* b2   = (const float*)d_in[12];
    const float* g2   = (const float*)d_in[13];
    const float* be2  = (const float*)d_in[14];
    float* out = (float*)d_out;

    char* ws = (char*)d_ws;
    size_t off = 0;
    u16*   xlr  = (u16*)(ws + off);   off += (size_t)NNODES * 1024 * 2;   // 41 MB
    u16*   xb   = (u16*)(ws + off);   off += (size_t)NNODES * 128 * 2;    // 5.1 MB
    float* hbuf = (float*)(ws + off); off += (size_t)NNODES * 128 * 4;    // 10.2 MB
    u16*   Bt1  = (u16*)(ws + off);   off += (size_t)1024 * 128 * 2;
    u16*   Bt2  = (u16*)(ws + off);   off += (size_t)1024 * 128 * 2;
    int*   deg  = (int*)(ws + off);   off += (size_t)NNODES * 4;
    int*   rowp = (int*)(ws + off);   off += (size_t)(NNODES + 1) * 4;
    int*   cur  = (int*)(ws + off);   off += (size_t)NNODES * 4;
    int*   col  = (int*)(ws + off);   off += (size_t)ETOT * 4;

    // CSR build (same graph both layers)
    k_init_deg<<<(NNODES + 255) / 256, 256, 0, stream>>>(deg);
    k_hist<<<(NEDGES + 255) / 256, 256, 0, stream>>>(dst, deg);
    k_scan<<<1, 1024, 0, stream>>>(deg, rowp, cur);
    k_scatter<<<(ETOT + 255) / 256, 256, 0, stream>>>(src, dst, col, cur);

    // conversions
    k_cvt_x<<<(NNODES * 128 / 4 + 255) / 256, 256, 0, stream>>>(x, xb, NNODES * 128 / 4);
    k_cvt_w<<<(1024 * 128 + 255) / 256, 256, 0, stream>>>(Wl1, Wr1, Bt1);
    k_cvt_w<<<(1024 * 128 + 255) / 256, 256, 0, stream>>>(Wl2, Wr2, Bt2);

    dim3 ggrid(8, (NNODES + 127) / 128);  // 8 x 157

    // layer 1
    k_gemm_f16<<<ggrid, 256, 0, stream>>>(xb, Bt1, xlr, NNODES);
    k_attn<<<NNODES / 4, 256, 0, stream>>>(xlr, att1, b1, g1, be1, rowp, col,
                                           x, hbuf, xb /*fp16 out for layer2*/, 1);
    // layer 2
    k_gemm_f16<<<ggrid, 256, 0, stream>>>(xb, Bt2, xlr, NNODES);
    k_attn<<<NNODES / 4, 256, 0, stream>>>(xlr, att2, b2, g2, be2, rowp, col,
                                           hbuf, out, (u16*)nullptr, 0);
}